// Round 13
// baseline (74.181 us; speedup 1.0000x reference)
//
#include <hip/hip_runtime.h>

#define NB 16           // B images
#define NP 16000        // proposals per image (= 250*64)
#define NG 256          // gt boxes per image
#define NM (NP + NG)    // proposals + gt = 16256
#define NSTRIP 254      // NM / 64
#define NS 512          // samples per image
#define NCLS 91
#define SL1_BETA (1.0f/9.0f)
#define MATCHX 64       // 64 blocks x 4 waves = 256 strips (254 used)
#define STATSX 4        // stats blocks per image

__device__ __forceinline__ float rlf(float v, int l) {
    return __int_as_float(__builtin_amdgcn_readlane(__float_as_int(v), l));
}

// ---------------------------------------------------------------------------
// K1 = match + softmax-stats.
// match: wave-per-strip (64 proposals). Lane holds 4 GTs in REGISTERS
//   (g = lane, lane+64, lane+128, lane+192) — no LDS, no s_load in loop.
//   Phase 1 (branch-free): per proposal i, 5 readlanes broadcast the proposal;
//   4 ballots of the exact predicate iou>=0.5 <=> fmaf(inter,3,-(ga+ap))>=0;
//   q = OR != 0 sets posword bit (SALU). 256 pairs per ~53 VALU.
//   Phase 2 (positives only): per-lane exact best among its 4 GTs (proven
//   cross-product compare, ascending g within lane), then 6-step shfl_xor
//   argmax carrying (ib,ub,g) with min-g on comparator-tie == first-max rule.
//   Label from register-held per-lane labels via readfirstlane + readlane.
//   GT strips 250..253: self-match (IoU=1.0 beats all distinct boxes) direct.
// stats: per-row logsumexp (R11/R12-proven rider).
// grid = (68, NB) x 256. No LDS in match, no atomics, no fences.
// ---------------------------------------------------------------------------
__global__ __launch_bounds__(256) void k1_kernel(
    const float4* __restrict__ props4,      // [NB*NP]
    const float4* __restrict__ gt4,         // [NB*NG]
    const int*    __restrict__ gt_labels,   // [NB*NG]
    const float*  __restrict__ logits,      // [NB*NS, NCLS]
    unsigned int* __restrict__ posinfo,     // [NB*NM]
    float*        __restrict__ stats)       // [NB*NS]
{
    const int b    = blockIdx.y;
    const int bx   = blockIdx.x;
    const int tid  = threadIdx.x;
    const int lane = tid & 63;
    const int wid  = tid >> 6;

    if (bx >= MATCHX) {
        // ---- softmax stats: 64 blocks x 4 waves; 32 rows per wave ----
        const int sid = (bx - MATCHX) * NB + b;          // 0..63
        for (int rr = 0; rr < 32; ++rr) {
            const int r = sid * 128 + wid * 32 + rr;
            const float* row = logits + (size_t)r * NCLS;
            float a = (lane < NCLS)      ? row[lane]      : -3.0e38f;
            float c = (lane + 64 < NCLS) ? row[lane + 64] : -3.0e38f;
            float mx = fmaxf(a, c);
            #pragma unroll
            for (int o = 32; o; o >>= 1) mx = fmaxf(mx, __shfl_xor(mx, o, 64));
            float ss = 0.0f;
            if (lane < NCLS)      ss += expf(a - mx);
            if (lane + 64 < NCLS) ss += expf(c - mx);
            #pragma unroll
            for (int o = 32; o; o >>= 1) ss += __shfl_xor(ss, o, 64);
            if (lane == 0) stats[r] = mx + logf(ss);
        }
        return;
    }

    const int strip = bx * 4 + wid;
    if (strip >= NSTRIP) return;                 // wave-uniform

    const float4* __restrict__ gtb = gt4 + (size_t)b * NG;

    if (strip >= 250) {                          // GT self-rows: match = self
        const int g = strip * 64 + lane - NP;    // 0..255 (NP = 250*64)
        posinfo[(size_t)b * NM + strip * 64 + lane] =
            ((unsigned)g << 16) | (unsigned)gt_labels[b * NG + g];
        return;
    }

    // per-lane GT registers (whole wave holds all 256 GTs)
    const float4 g0 = gtb[lane],       g1 = gtb[64 + lane];
    const float4 g2 = gtb[128 + lane], g3 = gtb[192 + lane];
    const float  a0 = (g0.z - g0.x) * (g0.w - g0.y);
    const float  a1 = (g1.z - g1.x) * (g1.w - g1.y);
    const float  a2 = (g2.z - g2.x) * (g2.w - g2.y);
    const float  a3 = (g3.z - g3.x) * (g3.w - g3.y);
    const int    l0 = gt_labels[b * NG + lane];
    const int    l1 = gt_labels[b * NG + 64 + lane];
    const int    l2 = gt_labels[b * NG + 128 + lane];
    const int    l3 = gt_labels[b * NG + 192 + lane];

    // per-lane proposal of this strip (strip < 250 -> all plain proposals)
    const int j = strip * 64 + lane;
    const float4 pv = props4[(size_t)b * NP + j];
    const float  pa = (pv.z - pv.x) * (pv.w - pv.y);

    // ---- phase 1: positivity posword (branch-free per proposal) ----
    unsigned long long posw = 0ull;
    #pragma unroll 4
    for (int i = 0; i < 64; ++i) {
        const float px0 = rlf(pv.x, i), py0 = rlf(pv.y, i);
        const float px1 = rlf(pv.z, i), py1 = rlf(pv.w, i);
        const float pap = rlf(pa, i);
#define GRP(GV, GA)                                                          \
        ({ float lx = fmaxf(GV.x, px0), ly = fmaxf(GV.y, py0);               \
           float rx = fminf(GV.z, px1), ry = fminf(GV.w, py1);               \
           float ww = fmaxf(rx - lx, 0.0f), hh = fmaxf(ry - ly, 0.0f);       \
           float inter = ww * hh;                                            \
           __ballot(fmaf(inter, 3.0f, -(GA + pap)) >= 0.0f); })
        unsigned long long q = GRP(g0, a0) | GRP(g1, a1) | GRP(g2, a2) | GRP(g3, a3);
#undef GRP
        if (q) posw |= 1ull << i;                // uniform -> SALU cselect
    }

    // ---- phase 2: exact argmax for positive proposals only ----
    unsigned info = 0;                           // my proposal's output
    unsigned long long w = posw;
    while (w) {
        const int i = __builtin_ctzll(w); w &= w - 1;
        const float px0 = rlf(pv.x, i), py0 = rlf(pv.y, i);
        const float px1 = rlf(pv.z, i), py1 = rlf(pv.w, i);
        const float pap = rlf(pa, i);
        float ib = -1.0f, ub = 1.0f; int gs = 0;
#define EVAL(GV, GA, GG)                                                     \
        { float lx = fmaxf(GV.x, px0), ly = fmaxf(GV.y, py0);                \
          float rx = fminf(GV.z, px1), ry = fminf(GV.w, py1);                \
          float ww = fmaxf(rx - lx, 0.0f), hh = fmaxf(ry - ly, 0.0f);        \
          float inter = ww * hh;                                             \
          float u = (GA + pap) - inter;                                      \
          /* inter/u > ib/ub <=> inter*ub > ib*u (u,ub>0); ascending g +     \
             strict improve == first-max tie rule within the lane */         \
          if (inter * ub > ib * u) { ib = inter; ub = u; gs = (GG); } }
        EVAL(g0, a0, lane)
        EVAL(g1, a1, 64 + lane)
        EVAL(g2, a2, 128 + lane)
        EVAL(g3, a3, 192 + lane)
#undef EVAL
        #pragma unroll
        for (int o = 1; o < 64; o <<= 1) {       // butterfly argmax
            float oib = __shfl_xor(ib, o, 64);
            float oub = __shfl_xor(ub, o, 64);
            int   og  = __shfl_xor(gs, o, 64);
            float pA = oib * ub, pB = ib * oub;  // other better iff pA > pB
            bool take = (pA > pB) || (!(pB > pA) && og < gs);  // min-g on tie
            if (take) { ib = oib; ub = oub; gs = og; }
        }
        const int gsu = __builtin_amdgcn_readfirstlane(gs);
        const int kk = gsu >> 6, ll = gsu & 63;
        const int lv = (kk == 0) ? l0 : (kk == 1) ? l1 : (kk == 2) ? l2 : l3;
        const int lbl = __builtin_amdgcn_readlane(lv, ll);
        if (lane == i) info = ((unsigned)gsu << 16) | (unsigned)lbl;
    }
    posinfo[(size_t)b * NM + j] = info;          // coalesced, 0 = negative
}

// ---------------------------------------------------------------------------
// K2: per-image balanced sampler (deterministic first-k) + box encoding.
// Unchanged from R8 (proven). grid = NB x 256.
// ---------------------------------------------------------------------------
__global__ __launch_bounds__(256) void sample_kernel(
    const float4* __restrict__ props4,
    const float4* __restrict__ gt4,
    const float*  __restrict__ gt_thetas,
    const unsigned int* __restrict__ posinfo,
    int*   __restrict__ labels_out,   // [NB*NS]
    float* __restrict__ regt_out)     // [NB*NS*5]
{
    __shared__ int sampled[NS];
    __shared__ int wsum[4];

    const int b    = blockIdx.x;
    const int tid  = threadIdx.x;
    const int lane = tid & 63;
    const int wid  = tid >> 6;
    const unsigned* P = posinfo + (size_t)b * NM;
    const int base = tid * 64;

    unsigned long long pm = 0ull;
    int cn = 0;
    if (tid < NSTRIP) {
        const uint4* Pv = reinterpret_cast<const uint4*>(P + base);
        #pragma unroll
        for (int q = 0; q < 16; ++q) {
            uint4 v = Pv[q];
            int e = q * 4;
            if (v.x) pm |= 1ull << (e + 0);
            if (v.y) pm |= 1ull << (e + 1);
            if (v.z) pm |= 1ull << (e + 2);
            if (v.w) pm |= 1ull << (e + 3);
        }
        cn = 64 - __popcll(pm);
    }
    int cp = (tid < NSTRIP) ? __popcll(pm) : 0;
    int val  = (cp << 16) | cn;
    int incl = val;
    #pragma unroll
    for (int off = 1; off < 64; off <<= 1) {
        int u = __shfl_up(incl, off, 64);
        if (lane >= off) incl += u;
    }
    if (lane == 63) wsum[wid] = incl;
    __syncthreads();
    int wbase = 0;
    #pragma unroll
    for (int w = 0; w < 4; ++w) if (w < wid) wbase += wsum[w];
    int tot  = wsum[0] + wsum[1] + wsum[2] + wsum[3];
    int excl = wbase + incl - val;
    int rp = excl >> 16, rn = excl & 0xffff;
    int posT = tot >> 16, negT = tot & 0xffff;
    int np = posT < 128 ? posT : 128;          // n_pos = min(pos_total, S/4)
    int nn = NS - np; if (nn > negT) nn = negT;

    if (tid < NSTRIP) {
        #pragma unroll 4
        for (int e = 0; e < 64; ++e) {
            int idx = base + e;
            if ((pm >> e) & 1ull) {
                if (rp < np) sampled[rp + (rn < nn ? rn : nn)] = idx;
                rp++;
            } else {
                if (rn < nn) sampled[rn + (rp < np ? rp : np)] = idx;
                rn++;
            }
        }
    }
    __syncthreads();
    // Fallback fill (unreachable with this data): unselected ascending.
    if (tid == 0 && np + nn < NS) {
        int cpp = 0, cnn = 0, i = np + nn;
        for (int idx = 0; idx < NM && i < NS; ++idx) {
            bool p = P[idx] != 0;
            bool sel;
            if (p) { sel = cpp < np; cpp++; } else { sel = cnn < nn; cnn++; }
            if (!sel) sampled[i++] = idx;
        }
    }
    __syncthreads();

    for (int i = tid; i < NS; i += 256) {
        int idx = sampled[i];
        unsigned info = P[idx];
        int lbl = 0;
        if (info) {
            int m = info >> 16; lbl = info & 0xffff;
            float4 pv = (idx < NP) ? props4[(size_t)b * NP + idx]
                                   : gt4[(size_t)b * NG + (idx - NP)];
            float4 rv = gt4[(size_t)b * NG + m];
            float pw = pv.z - pv.x, ph = pv.w - pv.y;
            float px = pv.x + 0.5f * pw, py = pv.y + 0.5f * ph;
            float gw = rv.z - rv.x, gh = rv.w - rv.y;
            float gx = rv.x + 0.5f * gw, gy = rv.y + 0.5f * gh;
            float* o = regt_out + ((size_t)b * NS + i) * 5;
            o[0] = 10.0f * (gx - px) / pw;
            o[1] = 10.0f * (gy - py) / ph;
            o[2] = 5.0f * logf(gw / pw);
            o[3] = 5.0f * logf(gh / ph);
            o[4] = gt_thetas[b * NG + m];
        }
        labels_out[b * NS + i] = lbl;
    }
}

// ---------------------------------------------------------------------------
// K3: label-dependent loss, thread-per-row (stats precomputed in K1).
// 32 blocks x 256; per-block float2 partial. No atomics.
// ---------------------------------------------------------------------------
__global__ __launch_bounds__(256) void loss_kernel(
    const float* __restrict__ logits,     // [N, 91]
    const float* __restrict__ boxreg,     // [N, 455]
    const int*   __restrict__ labs,       // [N]
    const float* __restrict__ regt,       // [N, 5]
    const float* __restrict__ stats,      // [N]
    float2* __restrict__ partials)        // [32]
{
    const int tid  = threadIdx.x;
    const int lane = tid & 63;
    const int wid  = tid >> 6;
    const int r    = blockIdx.x * 256 + tid;         // N = 32*256 = 8192

    const int lab = labs[r];
    float cls = stats[r] - logits[(size_t)r * NCLS + lab];
    float box = 0.0f;
    if (lab > 0) {
        const float* pr = boxreg + (size_t)r * (NCLS * 5) + lab * 5;
        const float* tg = regt + (size_t)r * 5;
        #pragma unroll
        for (int k = 0; k < 5; ++k) {
            float d  = pr[k] - tg[k];
            float ad = fabsf(d);
            box += (ad < SL1_BETA) ? 0.5f * d * d / SL1_BETA : ad - 0.5f * SL1_BETA;
        }
    }
    #pragma unroll
    for (int o = 32; o; o >>= 1) {
        cls += __shfl_xor(cls, o, 64);
        box += __shfl_xor(box, o, 64);
    }
    __shared__ float cc[4], bb[4];
    if (lane == 0) { cc[wid] = cls; bb[wid] = box; }
    __syncthreads();
    if (tid == 0)
        partials[blockIdx.x] = make_float2(cc[0] + cc[1] + cc[2] + cc[3],
                                           bb[0] + bb[1] + bb[2] + bb[3]);
}

// ---------------------------------------------------------------------------
// K4: reduce 32 float2 partials -> 2 outputs. 1 block x 64.
// ---------------------------------------------------------------------------
__global__ void final_kernel(const float2* __restrict__ partials,
                             float* __restrict__ out)
{
    const int tid = threadIdx.x;
    float2 v = (tid < 32) ? partials[tid] : make_float2(0.f, 0.f);
    float c = v.x, bx = v.y;
    #pragma unroll
    for (int o = 32; o; o >>= 1) {
        c  += __shfl_xor(c, o, 64);
        bx += __shfl_xor(bx, o, 64);
    }
    if (tid == 0) {
        const float invN = 1.0f / (float)(NB * NS);
        out[0] = c * invN;
        out[1] = bx * invN;
    }
}

// ---------------------------------------------------------------------------
extern "C" void kernel_launch(void* const* d_in, const int* in_sizes, int n_in,
                              void* d_out, int out_size, void* d_ws, size_t ws_size,
                              hipStream_t stream)
{
    const float* class_logits   = (const float*)d_in[0];  // [NB*NS, 91]
    const float* box_regression = (const float*)d_in[1];  // [NB*NS, 455]
    const float4* props4        = (const float4*)d_in[2]; // [NB, NP]
    const float4* gt4           = (const float4*)d_in[3]; // [NB, NG]
    const float* gt_thetas      = (const float*)d_in[4];  // [NB, NG]
    const int*   gt_labels      = (const int*)d_in[5];    // [NB, NG]
    float* out = (float*)d_out;

    char* ws = (char*)d_ws;
    unsigned int* posinfo = (unsigned int*)ws;             // NB*NM u32
    char* pend = ws + (((size_t)NB * NM * 4 + 255) & ~255ull);
    float* stats = (float*)pend;                           // NB*NS f32
    int*   labs  = (int*)(pend + (((size_t)NB * NS * 4 + 255) & ~255ull));
    float* regt  = (float*)((char*)labs + (((size_t)NB * NS * 4 + 255) & ~255ull));
    float2* partials = (float2*)((char*)regt + (((size_t)NB * NS * 5 * 4 + 255) & ~255ull));

    hipLaunchKernelGGL(k1_kernel, dim3(MATCHX + STATSX, NB), dim3(256), 0, stream,
                       props4, gt4, gt_labels, class_logits, posinfo, stats);
    hipLaunchKernelGGL(sample_kernel, dim3(NB), dim3(256), 0, stream,
                       props4, gt4, gt_thetas, posinfo, labs, regt);
    hipLaunchKernelGGL(loss_kernel, dim3(32), dim3(256), 0, stream,
                       class_logits, box_regression, labs, regt, stats, partials);
    hipLaunchKernelGGL(final_kernel, dim3(1), dim3(64), 0, stream, partials, out);
}

// Round 14
// 60.286 us; speedup vs baseline: 1.2305x; 1.2305x over previous
//
#include <hip/hip_runtime.h>

#define NB 16           // B images
#define NP 16000        // proposals per image
#define NG 256          // gt boxes per image
#define NM (NP + NG)    // proposals + gt = 16256
#define NSTRIP 254      // NM / 64
#define NS 512          // samples per image
#define NCLS 91
#define SL1_BETA (1.0f/9.0f)
#define MATCHX 64       // match blocks per image (256 proposals each)
#define STATSX 4        // stats blocks per image

// ---------------------------------------------------------------------------
// K1 = match + softmax-stats rider.
// match (bx < 64): thread-per-proposal (R3's proven 85%-VALU memory pattern:
//   gbox/gar in LDS, single broadcast address = conflict-free). Inner loop is
//   the R5-proven exact predicate ONLY (~13 VALU/pair):
//     iou >= 0.5  <=>  3*inter >= ap+ga   via  fmaf(inter,3,-tt) >= 0
//   Qualifier bitmasks kept in qm[8] REGISTERS (full unroll -> compile-time
//   indices; no LDS stash, no extra LDS-pipe pressure). qcnt==1 -> argmax =
//   that bit (global max qualifies whenever any qualifier exists). qcnt>1
//   (rare) -> exact cross-product argmax over set bits (ascending g + strict
//   improve = first-max tie rule). GT self-rows flow through the generic path.
//   Output: (gstar<<16)|label, 0 = negative.
// stats (bx >= 64): per-row logsumexp (R11-R13 proven rider; hides under match).
// grid = (68, NB) x 256. No atomics, no fences.
// ---------------------------------------------------------------------------
__global__ __launch_bounds__(256) void k1_kernel(
    const float4* __restrict__ props4,      // [NB*NP]
    const float4* __restrict__ gt4,         // [NB*NG]
    const int*    __restrict__ gt_labels,   // [NB*NG]
    const float*  __restrict__ logits,      // [NB*NS, NCLS]
    unsigned int* __restrict__ posinfo,     // [NB*NM]
    float*        __restrict__ stats)       // [NB*NS]
{
    const int b    = blockIdx.y;
    const int bx   = blockIdx.x;
    const int tid  = threadIdx.x;
    const int lane = tid & 63;
    const int wid  = tid >> 6;

    if (bx >= MATCHX) {
        // ---- softmax stats: 64 blocks x 4 waves; 32 rows per wave ----
        const int sid = (bx - MATCHX) * NB + b;          // 0..63
        for (int rr = 0; rr < 32; ++rr) {
            const int r = sid * 128 + wid * 32 + rr;
            const float* row = logits + (size_t)r * NCLS;
            float a = (lane < NCLS)      ? row[lane]      : -3.0e38f;
            float c = (lane + 64 < NCLS) ? row[lane + 64] : -3.0e38f;
            float mx = fmaxf(a, c);
            #pragma unroll
            for (int o = 32; o; o >>= 1) mx = fmaxf(mx, __shfl_xor(mx, o, 64));
            float ss = 0.0f;
            if (lane < NCLS)      ss += expf(a - mx);
            if (lane + 64 < NCLS) ss += expf(c - mx);
            #pragma unroll
            for (int o = 32; o; o >>= 1) ss += __shfl_xor(ss, o, 64);
            if (lane == 0) stats[r] = mx + logf(ss);
        }
        return;
    }

    // ---- match ----
    __shared__ float4 gbox[NG];     // 4 KB
    __shared__ float  gar[NG];      // 1 KB

    {   // 256 threads load 256 gts
        const float4 v = gt4[(size_t)b * NG + tid];
        gbox[tid] = v;
        gar[tid]  = (v.z - v.x) * (v.w - v.y);
    }
    __syncthreads();

    const int j = bx * 256 + tid;
    if (j >= NM) return;                       // wave-uniform (NM % 64 == 0)

    const float4 pb = (j < NP) ? props4[(size_t)b * NP + j]
                               : gt4[(size_t)b * NG + (j - NP)];
    const float ap = (pb.z - pb.x) * (pb.w - pb.y);

    unsigned qm[8];                            // register-resident (unrolled)
    int qcnt = 0, gf = 0;
    #pragma unroll
    for (int w = 0; w < 8; ++w) {
        unsigned m = 0;
        #pragma unroll
        for (int t = 0; t < 32; ++t) {
            const int g = w * 32 + t;
            const float4 gb = gbox[g];         // broadcast ds_read_b128
            const float  ga = gar[g];          // broadcast ds_read_b32
            float lx = fmaxf(gb.x, pb.x), ly = fmaxf(gb.y, pb.y);
            float rx = fminf(gb.z, pb.z), ry = fminf(gb.w, pb.w);
            float ww = fmaxf(rx - lx, 0.0f), hh = fmaxf(ry - ly, 0.0f);
            float inter = ww * hh;
            float tt = ga + ap;
            if (fmaf(inter, 3.0f, -tt) >= 0.0f) m |= (1u << t);
        }
        qm[w] = m;
        if (qcnt == 0 && m) gf = w * 32 + (__ffs(m) - 1);
        qcnt += __popc(m);
    }

    unsigned info = 0;
    if (qcnt > 0) {
        int gstar = gf;
        if (qcnt > 1) {                        // rare: exact argmax over set bits
            float ib = -1.0f, ub = 1.0f; gstar = 0;
            #pragma unroll
            for (int w = 0; w < 8; ++w) {
                unsigned m = qm[w];
                while (m) {
                    int t = __ffs(m) - 1; m &= m - 1;
                    int g = w * 32 + t;
                    const float4 gb = gbox[g];
                    float lx = fmaxf(gb.x, pb.x), ly = fmaxf(gb.y, pb.y);
                    float rx = fminf(gb.z, pb.z), ry = fminf(gb.w, pb.w);
                    float ww = fmaxf(rx - lx, 0.0f), hh = fmaxf(ry - ly, 0.0f);
                    float inter = ww * hh;
                    float u = (gar[g] + ap) - inter;
                    // inter/u > ib/ub <=> inter*ub > ib*u ; ascending g +
                    // strict improve == first-max tie rule
                    if (inter * ub > ib * u) { ib = inter; ub = u; gstar = g; }
                }
            }
        }
        info = ((unsigned)gstar << 16) | (unsigned)gt_labels[b * NG + gstar];
    }
    posinfo[(size_t)b * NM + j] = info;        // coalesced, 0 = negative
}

// ---------------------------------------------------------------------------
// K2: fused per-image sampler + loss. grid = NB x 256.
// Sample phase: R8-proven (posmask rebuild from posinfo, shfl block-scan,
// direct-slot writes, fallback fill). Then each thread handles rows
// i = tid, tid+256 of its image: box-encode IN REGISTERS, CE from the
// precomputed stats, smooth-L1 vs boxreg gather; block-reduce -> partials[b].
// No labs/regt global round-trip. No atomics; fixed-order sums.
// ---------------------------------------------------------------------------
__global__ __launch_bounds__(256) void k2_kernel(
    const float4* __restrict__ props4,
    const float4* __restrict__ gt4,
    const float*  __restrict__ gt_thetas,
    const unsigned int* __restrict__ posinfo,
    const float*  __restrict__ logits,      // [N, 91]
    const float*  __restrict__ boxreg,      // [N, 455]
    const float*  __restrict__ stats,       // [N]
    float2* __restrict__ partials)          // [NB]
{
    __shared__ int sampled[NS];
    __shared__ int wsum[4];

    const int b    = blockIdx.x;
    const int tid  = threadIdx.x;
    const int lane = tid & 63;
    const int wid  = tid >> 6;
    const unsigned* P = posinfo + (size_t)b * NM;
    const int base = tid * 64;

    unsigned long long pm = 0ull;
    int cn = 0;
    if (tid < NSTRIP) {
        const uint4* Pv = reinterpret_cast<const uint4*>(P + base);
        #pragma unroll
        for (int q = 0; q < 16; ++q) {
            uint4 v = Pv[q];
            int e = q * 4;
            if (v.x) pm |= 1ull << (e + 0);
            if (v.y) pm |= 1ull << (e + 1);
            if (v.z) pm |= 1ull << (e + 2);
            if (v.w) pm |= 1ull << (e + 3);
        }
        cn = 64 - __popcll(pm);
    }
    int cp = (tid < NSTRIP) ? __popcll(pm) : 0;
    int val  = (cp << 16) | cn;
    int incl = val;
    #pragma unroll
    for (int off = 1; off < 64; off <<= 1) {
        int u = __shfl_up(incl, off, 64);
        if (lane >= off) incl += u;
    }
    if (lane == 63) wsum[wid] = incl;
    __syncthreads();
    int wbase = 0;
    #pragma unroll
    for (int w = 0; w < 4; ++w) if (w < wid) wbase += wsum[w];
    int tot  = wsum[0] + wsum[1] + wsum[2] + wsum[3];
    int excl = wbase + incl - val;
    int rp = excl >> 16, rn = excl & 0xffff;
    int posT = tot >> 16, negT = tot & 0xffff;
    int np = posT < 128 ? posT : 128;          // n_pos = min(pos_total, S/4)
    int nn = NS - np; if (nn > negT) nn = negT;

    if (tid < NSTRIP) {
        #pragma unroll 4
        for (int e = 0; e < 64; ++e) {
            int idx = base + e;
            if ((pm >> e) & 1ull) {
                if (rp < np) sampled[rp + (rn < nn ? rn : nn)] = idx;
                rp++;
            } else {
                if (rn < nn) sampled[rn + (rp < np ? rp : np)] = idx;
                rn++;
            }
        }
    }
    __syncthreads();
    // Fallback fill (unreachable with this data): unselected ascending.
    if (tid == 0 && np + nn < NS) {
        int cpp = 0, cnn = 0, i = np + nn;
        for (int idx = 0; idx < NM && i < NS; ++idx) {
            bool p = P[idx] != 0;
            bool sel;
            if (p) { sel = cpp < np; cpp++; } else { sel = cnn < nn; cnn++; }
            if (!sel) sampled[i++] = idx;
        }
    }
    __syncthreads();

    // ---- loss phase (2 rows per thread, all in registers) ----
    float cls_acc = 0.0f, box_acc = 0.0f;
    #pragma unroll
    for (int it = 0; it < 2; ++it) {
        const int i = tid + it * 256;
        const int r = b * NS + i;
        const int idx = sampled[i];
        const unsigned info = P[idx];
        int lbl = 0;
        if (info) lbl = info & 0xffff;
        cls_acc += stats[r] - logits[(size_t)r * NCLS + lbl];
        if (info) {
            const int m = info >> 16;
            float4 pv = (idx < NP) ? props4[(size_t)b * NP + idx]
                                   : gt4[(size_t)b * NG + (idx - NP)];
            float4 rv = gt4[(size_t)b * NG + m];
            float pw = pv.z - pv.x, ph = pv.w - pv.y;
            float px = pv.x + 0.5f * pw, py = pv.y + 0.5f * ph;
            float gw = rv.z - rv.x, gh = rv.w - rv.y;
            float gx = rv.x + 0.5f * gw, gy = rv.y + 0.5f * gh;
            float o0 = 10.0f * (gx - px) / pw;
            float o1 = 10.0f * (gy - py) / ph;
            float o2 = 5.0f * logf(gw / pw);
            float o3 = 5.0f * logf(gh / ph);
            float o4 = gt_thetas[b * NG + m];
            const float* pr = boxreg + (size_t)r * (NCLS * 5) + lbl * 5;
            float tg[5] = { o0, o1, o2, o3, o4 };
            #pragma unroll
            for (int k = 0; k < 5; ++k) {
                float d  = pr[k] - tg[k];
                float ad = fabsf(d);
                box_acc += (ad < SL1_BETA) ? 0.5f * d * d / SL1_BETA
                                           : ad - 0.5f * SL1_BETA;
            }
        }
    }
    #pragma unroll
    for (int o = 32; o; o >>= 1) {
        cls_acc += __shfl_xor(cls_acc, o, 64);
        box_acc += __shfl_xor(box_acc, o, 64);
    }
    __shared__ float cc[4], bb[4];
    if (lane == 0) { cc[wid] = cls_acc; bb[wid] = box_acc; }
    __syncthreads();
    if (tid == 0)
        partials[b] = make_float2(cc[0] + cc[1] + cc[2] + cc[3],
                                  bb[0] + bb[1] + bb[2] + bb[3]);
}

// ---------------------------------------------------------------------------
// K3: reduce NB float2 partials -> 2 outputs. 1 block x 64.
// ---------------------------------------------------------------------------
__global__ void final_kernel(const float2* __restrict__ partials,
                             float* __restrict__ out)
{
    const int tid = threadIdx.x;
    float2 v = (tid < NB) ? partials[tid] : make_float2(0.f, 0.f);
    float c = v.x, bx = v.y;
    #pragma unroll
    for (int o = 32; o; o >>= 1) {
        c  += __shfl_xor(c, o, 64);
        bx += __shfl_xor(bx, o, 64);
    }
    if (tid == 0) {
        const float invN = 1.0f / (float)(NB * NS);
        out[0] = c * invN;
        out[1] = bx * invN;
    }
}

// ---------------------------------------------------------------------------
extern "C" void kernel_launch(void* const* d_in, const int* in_sizes, int n_in,
                              void* d_out, int out_size, void* d_ws, size_t ws_size,
                              hipStream_t stream)
{
    const float* class_logits   = (const float*)d_in[0];  // [NB*NS, 91]
    const float* box_regression = (const float*)d_in[1];  // [NB*NS, 455]
    const float4* props4        = (const float4*)d_in[2]; // [NB, NP]
    const float4* gt4           = (const float4*)d_in[3]; // [NB, NG]
    const float* gt_thetas      = (const float*)d_in[4];  // [NB, NG]
    const int*   gt_labels      = (const int*)d_in[5];    // [NB, NG]
    float* out = (float*)d_out;

    char* ws = (char*)d_ws;
    unsigned int* posinfo = (unsigned int*)ws;             // NB*NM u32
    char* pend = ws + (((size_t)NB * NM * 4 + 255) & ~255ull);
    float* stats = (float*)pend;                           // NB*NS f32
    float2* partials = (float2*)(pend + (((size_t)NB * NS * 4 + 255) & ~255ull));

    hipLaunchKernelGGL(k1_kernel, dim3(MATCHX + STATSX, NB), dim3(256), 0, stream,
                       props4, gt4, gt_labels, class_logits, posinfo, stats);
    hipLaunchKernelGGL(k2_kernel, dim3(NB), dim3(256), 0, stream,
                       props4, gt4, gt_thetas, posinfo, class_logits,
                       box_regression, stats, partials);
    hipLaunchKernelGGL(final_kernel, dim3(1), dim3(64), 0, stream, partials, out);
}